// Round 15
// baseline (670.351 us; speedup 1.0000x reference)
//
#include <hip/hip_runtime.h>
#include <cstddef>
#include <cstdint>

#define B_ 64
#define T_ 800
#define D_ 80
#define H_ 128
#define K_ 39
#define BT_ (B_ * T_)   // 51200

// CRF chunking
#define GCH_ 32          // steps per chunk
#define NCH_ 25          // ceil((T_-1)/GCH_)
#define CHF_ 1664        // f32 stride per chunk record (40*40 data + pad; scale at [1600])

// exp2 pre-scale constants.
#define NL2E_  (-1.44269504f)
#define N2L2E_ (-2.88539008f)
#define L2E_   (1.44269504f)

typedef _Float16 h2_t  __attribute__((ext_vector_type(2)));
typedef _Float16 f16x8 __attribute__((ext_vector_type(8)));
typedef float    f32x4 __attribute__((ext_vector_type(4)));
typedef uint32_t u32x4 __attribute__((ext_vector_type(4)));

__device__ __forceinline__ float fdot2_(h2_t a, h2_t b, float c) {
#if __has_builtin(__builtin_amdgcn_fdot2)
  return __builtin_amdgcn_fdot2(a, b, c, false);
#else
  return c + (float)a.x * (float)b.x + (float)a.y * (float)b.y;
#endif
}

__device__ __forceinline__ h2_t asH2u_(uint32_t u) { return __builtin_bit_cast(h2_t, u); }

__device__ __forceinline__ float ex2_(float x) {
#if __has_builtin(__builtin_amdgcn_exp2f)
  return __builtin_amdgcn_exp2f(x);
#else
  return __builtin_exp2f(x);
#endif
}
__device__ __forceinline__ float rcpf_(float x) {
#if __has_builtin(__builtin_amdgcn_rcpf)
  return __builtin_amdgcn_rcpf(x);
#else
  return 1.0f / x;
#endif
}
__device__ __forceinline__ float tanhf_(float x) { return 2.0f / (1.0f + __expf(-2.0f * x)) - 1.0f; }

__device__ __forceinline__ float laneb_(float v, int lane) {
  return __builtin_bit_cast(float, __builtin_amdgcn_readlane(__builtin_bit_cast(int, v), lane));
}
__device__ __forceinline__ uint32_t lanebu_(uint32_t v, int lane) {
  return (uint32_t)__builtin_amdgcn_readlane((int)v, lane);
}

// VALU lane-pair swap via DPP quad_perm[1,0,3,2] (0xB1): lane 2k <-> 2k+1.
__device__ __forceinline__ float dppswap1_(float v) {
  return __builtin_bit_cast(float,
    __builtin_amdgcn_mov_dpp(__builtin_bit_cast(int, v), 0xB1, 0xF, 0xF, true));
}

// LDS-only barrier: waits LDS ops but does NOT drain vmem.
__device__ __forceinline__ void barrier_lds_() {
  asm volatile("s_waitcnt lgkmcnt(0)" ::: "memory");
  __builtin_amdgcn_s_barrier();
}

// lstm lane->gate-rows mapping: wave w, lane L: unit = w*32 + (L>>1),
// role = L&1. role0 owns (i,g) rows, role1 owns (f,o). DPP(1) pairs them.
__device__ __forceinline__ void rows_of_(int tid, int& unit, int& role, int& r0, int& r1) {
  const int w = tid >> 6, L = tid & 63;
  unit = w * 32 + (L >> 1);
  role = L & 1;
  r0 = role * H_ + unit;            // i (role0) or f (role1)
  r1 = 2 * H_ + role * H_ + unit;   // g (role0) or o (role1)
}

// ---------------------------------------------------------------------------
// xw via MFMA 16x16x32 f16, PAIRED output layout, pre-scaled, LDS-bounced
// coalesced stores (verified R14).
// ---------------------------------------------------------------------------
__global__ __launch_bounds__(256, 1)
void xw_kernel(const float* __restrict__ x,
               const float* __restrict__ Wih_f, const float* __restrict__ Wih_b,
               _Float16* __restrict__ xw)
{
  const int dir = blockIdx.x & 1;
  const int mc  = blockIdx.x >> 1;           // 0..99
  const float* W = dir ? Wih_b : Wih_f;

  const int tid  = threadIdx.x;
  const int w    = tid >> 6;
  const int lane = tid & 63;
  const int lm   = lane & 15;
  const int quad = lane >> 4;
  const int selw = w >> 1;                   // 0: i/f (.x slot), 1: g/o (.y slot)
  const int rolw = w & 1;

  f16x8 Bf[8][3];
  #pragma unroll
  for (int nt = 0; nt < 8; ++nt) {
    const int r = w * 128 + nt * 16 + lm;
    const float fac = (r >= 256 && r < 384) ? N2L2E_ : NL2E_;   // g rows: -2log2e
    #pragma unroll
    for (int kt = 0; kt < 3; ++kt) {
      const int kb = kt * 32 + quad * 8;
      #pragma unroll
      for (int j = 0; j < 8; ++j) {
        const int k = kb + j;
        Bf[nt][kt][j] = (k < D_) ? (_Float16)(fac * W[(size_t)r * D_ + k]) : (_Float16)0.0f;
      }
    }
  }

  __shared__ alignas(16) _Float16 xs[128 * 96];   // 24 KB, K padded to 96
  __shared__ alignas(16) _Float16 xo[16 * 512];   // 16 KB store-coalescing tile
  for (int i = tid; i < 128 * 96; i += 256) xs[i] = (_Float16)0.0f;

  for (int cc = 0; cc < 4; ++cc) {
    const int base = mc * 512 + cc * 128;
    __syncthreads();
    {
      const float4* src = (const float4*)(x + (size_t)base * D_);
      for (int i = tid; i < 128 * D_ / 4; i += 256) {
        float4 v = src[i];
        const int row = i / 20, col = (i % 20) * 4;
        h2_t p0, p1;
        p0.x = (_Float16)v.x; p0.y = (_Float16)v.y;
        p1.x = (_Float16)v.z; p1.y = (_Float16)v.w;
        uint2 pk;
        pk.x = __builtin_bit_cast(uint32_t, p0);
        pk.y = __builtin_bit_cast(uint32_t, p1);
        *(uint2*)&xs[row * 96 + col] = pk;
      }
    }
    __syncthreads();

    #pragma unroll
    for (int mt = 0; mt < 8; ++mt) {
      f16x8 Af[3];
      #pragma unroll
      for (int kt = 0; kt < 3; ++kt)
        Af[kt] = *(const f16x8*)&xs[(mt * 16 + lm) * 96 + kt * 32 + quad * 8];

      f32x4 acc[8];
      #pragma unroll
      for (int nt = 0; nt < 8; ++nt) acc[nt] = (f32x4){0.f, 0.f, 0.f, 0.f};
      #pragma unroll
      for (int kt = 0; kt < 3; ++kt)
        #pragma unroll
        for (int nt = 0; nt < 8; ++nt)
          acc[nt] = __builtin_amdgcn_mfma_f32_16x16x32_f16(Af[kt], Bf[nt][kt], acc[nt], 0, 0, 0);

      // scatter tile into LDS (verified ptid mapping, local rows)
      #pragma unroll
      for (int nt = 0; nt < 8; ++nt) {
        const int unit = nt * 16 + lm;
        const int pcol = ((unit >> 5) * 64 + (unit & 31) * 2 + rolw) * 2 + selw;
        #pragma unroll
        for (int rg = 0; rg < 4; ++rg)
          xo[(quad * 4 + rg) * 512 + pcol] = (_Float16)acc[nt][rg];
      }
      __syncthreads();
      {
        const size_t gbase = ((size_t)dir * BT_ + base + mt * 16) * 512;
        const uint4* src4 = (const uint4*)xo;
        uint4* dst4 = (uint4*)(xw + gbase);
        #pragma unroll
        for (int i = 0; i < 4; ++i)
          dst4[tid + i * 256] = src4[tid + i * 256];
      }
      __syncthreads();   // xo reused next tile
    }
  }
}

// ---------------------------------------------------------------------------
// Recurrent LSTM: verified R4 433us kernel.
// ---------------------------------------------------------------------------
template<int USE_XW>
__global__ __launch_bounds__(256, 1)
void lstm_kernel(const float* __restrict__ x,
                 const float* __restrict__ Wih_f, const float* __restrict__ Whh_f,
                 const float* __restrict__ bih_f, const float* __restrict__ bhh_f,
                 const float* __restrict__ Wih_b, const float* __restrict__ Whh_b,
                 const float* __restrict__ bih_b, const float* __restrict__ bhh_b,
                 const _Float16* __restrict__ xw,
                 _Float16* __restrict__ hcat)
{
  const int bb  = blockIdx.x & 63;
  const int dir = blockIdx.x >> 6;
  const float* Whh = dir ? Whh_b : Whh_f;
  const float* Wih = dir ? Wih_b : Wih_f;
  const float* bih = dir ? bih_b : bih_f;
  const float* bhh = dir ? bhh_b : bhh_f;

  const int tid  = threadIdx.x;
  const int lane = tid & 63;
  int unit, role, r0, r1; rows_of_(tid, unit, role, r0, r1);
  const float s0 = NL2E_;
  const float s1 = role ? NL2E_ : N2L2E_;
  const float qk2 = role ? 0.0f : -1.0f;

  h2_t w0[64], w1[64];
  #pragma unroll
  for (int j = 0; j < 64; ++j) {
    float2 a = *(const float2*)(Whh + (size_t)r0 * H_ + 2 * j);
    float2 d = *(const float2*)(Whh + (size_t)r1 * H_ + 2 * j);
    w0[j].x = (_Float16)(s0 * a.x); w0[j].y = (_Float16)(s0 * a.y);
    w1[j].x = (_Float16)(s1 * d.x); w1[j].y = (_Float16)(s1 * d.y);
  }
  h2_t wx0[40], wx1[40];
  if (!USE_XW) {
    #pragma unroll
    for (int i = 0; i < 40; ++i) {
      float2 a = *(const float2*)(Wih + (size_t)r0 * D_ + 2 * i);
      float2 d = *(const float2*)(Wih + (size_t)r1 * D_ + 2 * i);
      wx0[i].x = (_Float16)(s0 * a.x); wx0[i].y = (_Float16)(s0 * a.y);
      wx1[i].x = (_Float16)(s1 * d.x); wx1[i].y = (_Float16)(s1 * d.y);
    }
  }
  const float bias0 = s0 * (bih[r0] + bhh[r0]);
  const float bias1 = s1 * (bih[r1] + bhh[r1]);

  __shared__ alignas(16) _Float16 hsf[2][H_];  // double-buffered h
  __shared__ uint32_t xs2[2][64];              // fallback x staging

  if (tid < H_) hsf[0][tid] = (_Float16)0.0f;
  if (!USE_XW && tid < 64) { xs2[0][tid] = 0u; xs2[1][tid] = 0u; }
  float c = 0.0f;   // role1 owns cell state of its unit

  const uint32_t* xwdu = (const uint32_t*)xw + ((size_t)dir * BT_ + (size_t)bb * T_) * 256;
  const float*    xb   = x + (size_t)bb * T_ * D_;
  _Float16*       hb   = hcat + (size_t)bb * T_ * (2 * H_) + dir * H_;

  _Float16* hbp = hb + (size_t)(dir ? (T_ - 1) : 0) * (2 * H_);
  const ptrdiff_t hstep = dir ? -(2 * H_) : (2 * H_);
  int xoff = (dir ? (T_ - 3) : 2) * 256 + tid;     // prefetch offset for ttc=2
  const int xstep = dir ? -256 : 256;

  uint32_t xwA = 0u, xwB = 0u;
  h2_t xpend; xpend.x = (_Float16)0.f; xpend.y = (_Float16)0.f;
  {
    const int tq0 = dir ? (T_ - 1) : 0;
    const int tq1 = dir ? (T_ - 2) : 1;
    if (USE_XW) {
      xwA = xwdu[(size_t)tq0 * 256 + tid];
      xwB = xwdu[(size_t)tq1 * 256 + tid];
    } else if (tid < 40) {
      float2 v0 = *(const float2*)(xb + (size_t)tq0 * D_ + 2 * tid);
      h2_t p; p.x = (_Float16)v0.x; p.y = (_Float16)v0.y;
      xs2[0][tid] = __builtin_bit_cast(uint32_t, p);
      float2 v1 = *(const float2*)(xb + (size_t)tq1 * D_ + 2 * tid);
      xpend.x = (_Float16)v1.x; xpend.y = (_Float16)v1.y;
    }
  }
  __syncthreads();

  auto step = [&](int tt, int par, uint32_t& xwreg) {
    float a0, a1, a2, a3, b0, b1, b2, b3;
    if (USE_XW) {
      const h2_t xv = asH2u_(xwreg);
      a0 = bias0 + (float)xv.x;
      b0 = bias1 + (float)xv.y;
      a1 = a2 = a3 = 0.f; b1 = b2 = b3 = 0.f;
      xwreg = xwdu[xoff];                         // prefetch; consumed 2 steps later
    } else {
      a0 = bias0; b0 = bias1;
      a1 = a2 = a3 = 0.f; b1 = b2 = b3 = 0.f;
      if (tid < 40) {
        xs2[par ^ 1][tid] = __builtin_bit_cast(uint32_t, xpend);
        const int ttc = (tt + 2 < T_) ? (tt + 2) : (T_ - 1);
        const int tq2 = dir ? (T_ - 1 - ttc) : ttc;
        float2 v = *(const float2*)(xb + (size_t)tq2 * D_ + 2 * tid);
        xpend.x = (_Float16)v.x; xpend.y = (_Float16)v.y;
      }
      uint32_t xreg = xs2[par][lane];
      #pragma unroll
      for (int j = 0; j < 40; j += 4) {
        h2_t q0 = asH2u_(lanebu_(xreg, j));
        h2_t q1 = asH2u_(lanebu_(xreg, j + 1));
        h2_t q2 = asH2u_(lanebu_(xreg, j + 2));
        h2_t q3 = asH2u_(lanebu_(xreg, j + 3));
        a0 = fdot2_(wx0[j],     q0, a0); b0 = fdot2_(wx1[j],     q0, b0);
        a1 = fdot2_(wx0[j + 1], q1, a1); b1 = fdot2_(wx1[j + 1], q1, b1);
        a2 = fdot2_(wx0[j + 2], q2, a2); b2 = fdot2_(wx1[j + 2], q2, b2);
        a3 = fdot2_(wx0[j + 3], q3, a3); b3 = fdot2_(wx1[j + 3], q3, b3);
      }
    }

    // h @ Whh^T via uniform-address LDS broadcasts, 8 chains depth 16.
    const u32x4* hq = (const u32x4*)hsf[par];
    #pragma unroll
    for (int g = 0; g < 16; ++g) {
      const u32x4 hv = hq[g];
      a0 = fdot2_(w0[4 * g + 0], asH2u_(hv[0]), a0);
      b0 = fdot2_(w1[4 * g + 0], asH2u_(hv[0]), b0);
      a1 = fdot2_(w0[4 * g + 1], asH2u_(hv[1]), a1);
      b1 = fdot2_(w1[4 * g + 1], asH2u_(hv[1]), b1);
      a2 = fdot2_(w0[4 * g + 2], asH2u_(hv[2]), a2);
      b2 = fdot2_(w1[4 * g + 2], asH2u_(hv[2]), b2);
      a3 = fdot2_(w0[4 * g + 3], asH2u_(hv[3]), a3);
      b3 = fdot2_(w1[4 * g + 3], asH2u_(hv[3]), b3);
    }
    const float ga = (a0 + a1) + (a2 + a3);   // -log2e * (i|f)
    const float gb = (b0 + b1) + (b2 + b3);   // -2log2e*g | -log2e*o

    const float ea = ex2_(ga);
    const float sg = rcpf_(1.0f + ea);
    const float gbc = fminf(fmaxf(gb, -34.6f), 34.6f);
    const float eb = ex2_(gbc);
    const float qv = fmaf(qk2, eb, 1.0f) * rcpf_(1.0f + eb);
    const float ex = dppswap1_(sg * qv);      // role1 receives p = sig(i)*tanh(g)
    c = fmaf(sg, c, ex);                      // role1: sig(f)*c + p (role0 benign)
    const float hn = qv * tanhf_(c);          // role1: sig(o)*tanh(c)
    if (role) {
      hsf[par ^ 1][unit] = (_Float16)hn;
      hbp[unit] = (_Float16)hn;               // async store, never drained
    }
    hbp += hstep;
    if (tt + 3 < T_) xoff += xstep;           // wave-uniform clamp-advance
    barrier_lds_();
  };

  for (int tb = 0; tb < T_; tb += 2) {
    step(tb,     0, xwA);
    step(tb + 1, 1, xwB);
  }
}

// ---------------------------------------------------------------------------
// Emissions via MFMA — retained ONLY for the small-workspace fallback path.
// ---------------------------------------------------------------------------
__global__ __launch_bounds__(256, 1)
void emis_kernel(const _Float16* __restrict__ hcat,
                 const float* __restrict__ Wp, const float* __restrict__ bp,
                 float* __restrict__ em)
{
  const int tid  = threadIdx.x;
  const int w    = tid >> 6;
  const int lane = tid & 63;
  const int lm   = lane & 15;
  const int quad = lane >> 4;

  f16x8 Bf[3][8];
  float bias[3];
  #pragma unroll
  for (int nt = 0; nt < 3; ++nt) {
    const int n = nt * 16 + lm;
    const bool valid = n < K_;
    bias[nt] = valid ? bp[n] : 0.0f;
    #pragma unroll
    for (int kt = 0; kt < 8; ++kt) {
      const int kb = kt * 32 + quad * 8;
      #pragma unroll
      for (int j = 0; j < 8; ++j)
        Bf[nt][kt][j] = valid ? (_Float16)Wp[(size_t)n * 256 + kb + j] : (_Float16)0.0f;
    }
  }

  #pragma unroll
  for (int q = 0; q < 4; ++q) {
    const int mt  = blockIdx.x * 16 + w * 4 + q;
    const int bt0 = mt * 16;

    f16x8 Af[8];
    const _Float16* ab = hcat + ((size_t)bt0 + lm) * 256;
    #pragma unroll
    for (int kt = 0; kt < 8; ++kt)
      Af[kt] = *(const f16x8*)(ab + kt * 32 + quad * 8);

    f32x4 acc[3];
    #pragma unroll
    for (int nt = 0; nt < 3; ++nt) acc[nt] = (f32x4){0.f, 0.f, 0.f, 0.f};
    #pragma unroll
    for (int kt = 0; kt < 8; ++kt)
      #pragma unroll
      for (int nt = 0; nt < 3; ++nt)
        acc[nt] = __builtin_amdgcn_mfma_f32_16x16x32_f16(Af[kt], Bf[nt][kt], acc[nt], 0, 0, 0);

    #pragma unroll
    for (int nt = 0; nt < 3; ++nt) {
      const int n = nt * 16 + lm;
      if (n < K_) {
        #pragma unroll
        for (int rg = 0; rg < 4; ++rg) {
          const int row = bt0 + quad * 4 + rg;
          em[(size_t)row * K_ + n] = acc[nt][rg] + bias[nt];
        }
      }
    }
  }
}

// ---------------------------------------------------------------------------
// R15: CRF chunked partial products WITH FUSED EMISSIONS. Each chunk wave
// computes its own 32-row em tile from hcat @ Wp^T + bp (same MFMA fragment
// layout and kt-order as the verified emis kernel -> same f32 rounding),
// stages it in LDS for the product loop, and writes it to the global em
// buffer for crf_comb. Chunk c=0 additionally computes the t=0 row via f16
// dots (for comb's alpha0 / numerator edge terms). The standalone emis
// dispatch is deleted from the big path.
// ---------------------------------------------------------------------------
__global__ __launch_bounds__(64, 1)
void crf_chunk_kernel(const _Float16* __restrict__ hcat,
                      const float* __restrict__ Wp, const float* __restrict__ bp,
                      const int* __restrict__ lengths,
                      const float* __restrict__ trans,
                      float* __restrict__ em,
                      float* __restrict__ Pbuf)
{
  const int b    = blockIdx.x / NCH_;
  const int c    = blockIdx.x % NCH_;
  const int lane = threadIdx.x;          // 0..63
  const int lm   = lane & 15;
  const int quad = lane >> 4;
  const int len  = lengths[b];
  const int t0   = 1 + c * GCH_;
  int t1 = 1 + (c + 1) * GCH_;
  if (t1 > T_)  t1 = T_;
  if (t1 > len) t1 = len;

  // Wp B-fragments (emis layout): Bp[nt][kt][j] = Wp[n*256 + kt*32+quad*8+j].
  f16x8 Bp[3][8];
  float bias[3];
  #pragma unroll
  for (int nt = 0; nt < 3; ++nt) {
    const int n = nt * 16 + lm;
    const bool valid = n < K_;
    bias[nt] = valid ? bp[n] : 0.0f;
    #pragma unroll
    for (int kt = 0; kt < 8; ++kt) {
      const int kb = kt * 32 + quad * 8;
      #pragma unroll
      for (int j = 0; j < 8; ++j)
        Bp[nt][kt][j] = valid ? (_Float16)Wp[(size_t)n * 256 + kb + j] : (_Float16)0.0f;
    }
  }

  // Constant ET B-fragments (verified R13 layout).
  f16x8 Bf[3][2];
  #pragma unroll
  for (int nt = 0; nt < 3; ++nt) {
    const int n = nt * 16 + lm;
    #pragma unroll
    for (int kf = 0; kf < 2; ++kf) {
      #pragma unroll
      for (int jj = 0; jj < 8; ++jj) {
        const int j = kf * 32 + quad * 8 + jj;
        Bf[nt][kf][jj] = (j < K_ && n < K_)
          ? (_Float16)__expf(trans[j * K_ + n]) : (_Float16)0.0f;
      }
    }
  }

  __shared__ alignas(16) _Float16 Plds[48 * 68];   // P, padded rows (R13)
  __shared__ alignas(16) float ems[GCH_ * 40];     // staged em tile (5 KB)
  for (int i = lane; i < 48 * 68; i += 64) Plds[i] = (_Float16)0.0f;
  if (lane < K_) Plds[lane * 68 + lane] = (_Float16)1.0f;   // identity

  // ---- fused emissions: 2 MFMA tiles covering rows [t0, t0+32) -----------
  #pragma unroll
  for (int mt2 = 0; mt2 < 2; ++mt2) {
    const int trow = t0 + mt2 * 16 + lm;             // A-frag row (abs t)
    const int trc  = (trow < T_) ? trow : (T_ - 1);  // clamp (c=24 touches 800)
    const _Float16* ar = hcat + ((size_t)b * T_ + trc) * 256;
    f16x8 Af[8];
    #pragma unroll
    for (int kt = 0; kt < 8; ++kt)
      Af[kt] = *(const f16x8*)(ar + kt * 32 + quad * 8);

    f32x4 acc[3];
    #pragma unroll
    for (int nt = 0; nt < 3; ++nt) acc[nt] = (f32x4){0.f, 0.f, 0.f, 0.f};
    #pragma unroll
    for (int kt = 0; kt < 8; ++kt)
      #pragma unroll
      for (int nt = 0; nt < 3; ++nt)
        acc[nt] = __builtin_amdgcn_mfma_f32_16x16x32_f16(Af[kt], Bp[nt][kt], acc[nt], 0, 0, 0);

    #pragma unroll
    for (int nt = 0; nt < 3; ++nt) {
      const int n = nt * 16 + lm;
      if (n < K_) {
        #pragma unroll
        for (int rg = 0; rg < 4; ++rg) {
          const int lr = mt2 * 16 + quad * 4 + rg;   // local row 0..31
          const int tr = t0 + lr;                    // absolute t
          const float val = acc[nt][rg] + bias[nt];
          ems[lr * 40 + n] = val;                    // LDS stage (always)
          if (tr < T_)
            em[((size_t)b * T_ + tr) * K_ + n] = val;   // global for comb
        }
      }
    }
  }

  // c==0: compute em row t=0 (39 f16 dots) for comb's alpha0/numerator.
  if (c == 0 && lane < K_) {
    const h2_t* h0 = (const h2_t*)(hcat + (size_t)b * T_ * 256);
    const float* wr = Wp + (size_t)lane * 256;
    float acc = bias[0] * 0.0f + bp[lane];
    float a1 = 0.f;
    #pragma unroll
    for (int k = 0; k < 128; k += 2) {
      h2_t wpk, wpk1;
      wpk.x  = (_Float16)wr[2 * k];     wpk.y  = (_Float16)wr[2 * k + 1];
      wpk1.x = (_Float16)wr[2 * k + 2]; wpk1.y = (_Float16)wr[2 * k + 3];
      acc = fdot2_(h0[k],     wpk,  acc);
      a1  = fdot2_(h0[k + 1], wpk1, a1);
    }
    em[(size_t)b * T_ * K_ + lane] = acc + a1;
  }
  asm volatile("s_waitcnt lgkmcnt(0)" ::: "memory");

  // ---- product loop (verified R13, e' sourced from the LDS stage) --------
  float sacc = 0.0f;
  for (int t = t0; t < t1; ++t) {
    float emv[3], e3[3];
    float mloc = -1e30f;
    #pragma unroll
    for (int nt = 0; nt < 3; ++nt) {
      const int col = nt * 16 + lm;
      emv[nt] = (col < K_) ? ems[(t - t0) * 40 + col] : -1e30f;
      mloc = fmaxf(mloc, emv[nt]);
    }
    #pragma unroll
    for (int off = 8; off >= 1; off >>= 1)
      mloc = fmaxf(mloc, __shfl_xor(mloc, off));     // reduce over lm group
    #pragma unroll
    for (int nt = 0; nt < 3; ++nt) {
      const int col = nt * 16 + lm;
      e3[nt] = (col < K_) ? ex2_((emv[nt] - mloc) * L2E_) : 0.0f;
    }

    // P @ ET : 9 output tiles x 2 k-fragments.
    f32x4 acc[3][3];
    #pragma unroll
    for (int mt = 0; mt < 3; ++mt)
      #pragma unroll
      for (int nt = 0; nt < 3; ++nt)
        acc[mt][nt] = (f32x4){0.f, 0.f, 0.f, 0.f};
    #pragma unroll
    for (int kf = 0; kf < 2; ++kf) {
      f16x8 Am[3];
      #pragma unroll
      for (int mt = 0; mt < 3; ++mt)
        Am[mt] = *(const f16x8*)&Plds[(mt * 16 + lm) * 68 + kf * 32 + quad * 8];
      #pragma unroll
      for (int mt = 0; mt < 3; ++mt)
        #pragma unroll
        for (int nt = 0; nt < 3; ++nt)
          acc[mt][nt] = __builtin_amdgcn_mfma_f32_16x16x32_f16(Am[mt], Bf[nt][kf], acc[mt][nt], 0, 0, 0);
    }

    // column-scale by e', per-step max renorm.
    float sv[3][3][4];
    float mx = 0.0f;
    #pragma unroll
    for (int mt = 0; mt < 3; ++mt)
      #pragma unroll
      for (int nt = 0; nt < 3; ++nt)
        #pragma unroll
        for (int rg = 0; rg < 4; ++rg) {
          const float s = acc[mt][nt][rg] * e3[nt];
          sv[mt][nt][rg] = s;
          mx = fmaxf(mx, s);
        }
    #pragma unroll
    for (int off = 32; off >= 1; off >>= 1)
      mx = fmaxf(mx, __shfl_xor(mx, off));
    const float rmx = rcpf_(mx);
    sacc += mloc - __logf(rmx);

    #pragma unroll
    for (int mt = 0; mt < 3; ++mt)
      #pragma unroll
      for (int nt = 0; nt < 3; ++nt)
        #pragma unroll
        for (int rg = 0; rg < 4; ++rg) {
          const int row = mt * 16 + quad * 4 + rg;
          const int col = nt * 16 + lm;
          Plds[row * 68 + col] = (_Float16)(sv[mt][nt][rg] * rmx);
        }
    asm volatile("s_waitcnt lgkmcnt(0)" ::: "memory");
  }

  // dump P (40x40 f32) + scale
  float* rec = Pbuf + ((size_t)(b * NCH_ + c)) * CHF_;
  for (int i = lane; i < 1600; i += 64) {
    const int r = i / 40, cc2 = i % 40;
    rec[i] = (float)Plds[r * 68 + cc2];
  }
  if (lane == 0) rec[1600] = sacc;
}

// ---------------------------------------------------------------------------
// CRF combine + numerator (verified R13, unchanged).
// ---------------------------------------------------------------------------
__global__ __launch_bounds__(256)
void crf_comb2_kernel(const float* __restrict__ em,
                      const int* __restrict__ labels, const int* __restrict__ lengths,
                      const float* __restrict__ start_t, const float* __restrict__ end_t,
                      const float* __restrict__ trans,
                      const float* __restrict__ Pbuf,
                      float* __restrict__ dn)
{
  const int b    = blockIdx.x;
  const int tid  = threadIdx.x;
  const int wv   = tid >> 6;
  const int lane = tid & 63;
  const int len  = lengths[b];
  const float* emb = em + (size_t)b * T_ * K_;

  __shared__ float s_num[3];
  __shared__ float s_den;

  if (wv == 0) {
    float a0 = (lane < K_) ? (start_t[lane] + emb[lane]) : -1e30f;
    float m = a0;
    #pragma unroll
    for (int off = 32; off > 0; off >>= 1) m = fmaxf(m, __shfl_xor(m, off));
    float av = __expf(a0 - m);        // lanes >= 39 -> 0
    float off_acc = m;

    for (int c = 0; c < NCH_; ++c) {
      const float* rec = Pbuf + ((size_t)(b * NCH_ + c)) * CHF_;
      const float pv = av;
      float s0 = 0.f, s1 = 0.f, s2 = 0.f, s3 = 0.f;
      #pragma unroll
      for (int j = 0; j < 36; j += 4) {
        s0 = fmaf(laneb_(pv, j),     rec[(j)     * 40 + lane], s0);
        s1 = fmaf(laneb_(pv, j + 1), rec[(j + 1) * 40 + lane], s1);
        s2 = fmaf(laneb_(pv, j + 2), rec[(j + 2) * 40 + lane], s2);
        s3 = fmaf(laneb_(pv, j + 3), rec[(j + 3) * 40 + lane], s3);
      }
      s0 = fmaf(laneb_(pv, 36), rec[36 * 40 + lane], s0);
      s1 = fmaf(laneb_(pv, 37), rec[37 * 40 + lane], s1);
      s2 = fmaf(laneb_(pv, 38), rec[38 * 40 + lane], s2);
      float vn = (lane < K_) ? ((s0 + s1) + (s2 + s3)) : 0.0f;
      float mx = vn;
      #pragma unroll
      for (int off = 32; off > 0; off >>= 1) mx = fmaxf(mx, __shfl_xor(mx, off));
      const float rmx = rcpf_(mx);
      av = vn * rmx;
      off_acc += rec[1600] - __logf(rmx);
    }

    float w = (lane < K_) ? av * __expf(end_t[lane]) : 0.0f;
    #pragma unroll
    for (int off = 32; off > 0; off >>= 1) w += __shfl_xor(w, off);
    if (lane == 0) s_den = off_acc + __logf(w);
  } else {
    const int idx = tid - 64;           // 0..191
    float acc = 0.0f;
    for (int t = 1 + idx; t < len; t += 192) {
      const int lp = labels[b * T_ + t - 1];
      const int lc = labels[b * T_ + t];
      acc += trans[lp * K_ + lc] + emb[(size_t)t * K_ + lc];
    }
    if (tid == 64) {
      const int l0 = labels[b * T_];
      const int ll = labels[b * T_ + len - 1];
      acc += start_t[l0] + emb[l0] + end_t[ll];
    }
    #pragma unroll
    for (int off = 32; off > 0; off >>= 1) acc += __shfl_xor(acc, off);
    if (lane == 0) s_num[wv - 1] = acc;
  }
  __syncthreads();
  if (tid == 0) dn[b] = s_den - (s_num[0] + s_num[1] + s_num[2]);
}

// ---------------------------------------------------------------------------
// Old sequential CRF (verified) — small-workspace fallback only.
// ---------------------------------------------------------------------------
__global__ __launch_bounds__(256)
void crf_dn_kernel(const float* __restrict__ em,
                   const int* __restrict__ labels, const int* __restrict__ lengths,
                   const float* __restrict__ start_t, const float* __restrict__ end_t,
                   const float* __restrict__ trans,
                   float* __restrict__ dn)
{
  const int b    = blockIdx.x;
  const int tid  = threadIdx.x;
  const int wv   = tid >> 6;
  const int lane = tid & 63;
  const int len  = lengths[b];
  const float* emb = em + (size_t)b * T_ * K_;

  __shared__ float s_num[3];
  __shared__ float s_den;

  if (wv == 0) {
    float et[K_];
    #pragma unroll
    for (int j = 0; j < K_; ++j)
      et[j] = (lane < K_) ? __expf(trans[j * K_ + lane]) : 0.0f;

    float a0 = (lane < K_) ? (start_t[lane] + emb[lane]) : -1e30f;
    float m = a0;
    #pragma unroll
    for (int off = 32; off > 0; off >>= 1) m = fmaxf(m, __shfl_xor(m, off));
    float v = __expf(a0 - m);
    float off_acc = m;

    auto ldc = [&](int t) -> float {
      const int tc = (t < len) ? t : (len - 1);
      return (lane < K_) ? emb[(size_t)tc * K_ + lane] : 0.0f;
    };

    float eA = ldc(1), eB = ldc(2), eC = ldc(3), eD = ldc(4);
    float eE = ldc(5), eF = ldc(6), eG = ldc(7), eH = ldc(8);

    auto stepden = [&](float& ereg, int tt) {
      const float emc = ereg;
      ereg = ldc(tt + 8);
      if (tt < len) {
        const float pv = v;
        float s0 = 0.f, s1 = 0.f, s2 = 0.f, s3 = 0.f;
        #pragma unroll
        for (int j = 0; j < 36; j += 4) {
          s0 = fmaf(laneb_(pv, j),     et[j],     s0);
          s1 = fmaf(laneb_(pv, j + 1), et[j + 1], s1);
          s2 = fmaf(laneb_(pv, j + 2), et[j + 2], s2);
          s3 = fmaf(laneb_(pv, j + 3), et[j + 3], s3);
        }
        s0 = fmaf(laneb_(pv, 36), et[36], s0);
        s1 = fmaf(laneb_(pv, 37), et[37], s1);
        s2 = fmaf(laneb_(pv, 38), et[38], s2);
        v = ((s0 + s1) + (s2 + s3)) * __expf(emc);
        if ((tt & 3) == 0) {
          const float sc = laneb_(v, 0);
          v *= 1.0f / sc;
          off_acc += __logf(sc);
        }
      }
    };

    for (int t = 1; t < len; t += 8) {
      stepden(eA, t);     stepden(eB, t + 1);
      stepden(eC, t + 2); stepden(eD, t + 3);
      stepden(eE, t + 4); stepden(eF, t + 5);
      stepden(eG, t + 6); stepden(eH, t + 7);
    }

    float w = (lane < K_) ? v * __expf(end_t[lane]) : 0.0f;
    #pragma unroll
    for (int off = 32; off > 0; off >>= 1) w += __shfl_xor(w, off);
    if (lane == 0) s_den = off_acc + __logf(w);
  } else {
    const int idx = tid - 64;
    float acc = 0.0f;
    for (int t = 1 + idx; t < len; t += 192) {
      const int lp = labels[b * T_ + t - 1];
      const int lc = labels[b * T_ + t];
      acc += trans[lp * K_ + lc] + emb[(size_t)t * K_ + lc];
    }
    if (tid == 64) {
      const int l0 = labels[b * T_];
      const int ll = labels[b * T_ + len - 1];
      acc += start_t[l0] + emb[l0] + end_t[ll];
    }
    #pragma unroll
    for (int off = 32; off > 0; off >>= 1) acc += __shfl_xor(acc, off);
    if (lane == 0) s_num[wv - 1] = acc;
  }
  __syncthreads();
  if (tid == 0) dn[b] = s_den - (s_num[0] + s_num[1] + s_num[2]);
}

// out = mean(dn) over the 64 batch elements (one wave).
__global__ void finalize_kernel(const float* __restrict__ dn, float* __restrict__ out)
{
  const int tid = threadIdx.x;   // 64
  float v = dn[tid];
  #pragma unroll
  for (int off = 32; off > 0; off >>= 1) v += __shfl_down(v, off);
  if (tid == 0) out[0] = v * (1.0f / 64.0f);
}

extern "C" void kernel_launch(void* const* d_in, const int* in_sizes, int n_in,
                              void* d_out, int out_size, void* d_ws, size_t ws_size,
                              hipStream_t stream)
{
  (void)in_sizes; (void)n_in; (void)out_size;
  const float* features = (const float*)d_in[0];
  const int*   lengths  = (const int*)d_in[1];
  const int*   labels   = (const int*)d_in[2];
  const float* Wih_f = (const float*)d_in[3];
  const float* Whh_f = (const float*)d_in[4];
  const float* bih_f = (const float*)d_in[5];
  const float* bhh_f = (const float*)d_in[6];
  const float* Wih_b = (const float*)d_in[7];
  const float* Whh_b = (const float*)d_in[8];
  const float* bih_b = (const float*)d_in[9];
  const float* bhh_b = (const float*)d_in[10];
  const float* Wp      = (const float*)d_in[11];
  const float* bp      = (const float*)d_in[12];
  const float* start_t = (const float*)d_in[13];
  const float* end_t   = (const float*)d_in[14];
  const float* trans   = (const float*)d_in[15];
  float* out = (float*)d_out;

  // ws layout (bytes): hcat f16 [0, 26214400) ; em f32 [26214400, +7987200) ;
  // dn 256 B ; xw f16 [34202112, +104857600). Pbuf overlays the xw region
  // (xw is dead after lstm completes; crf_chunk runs after lstm).
  char* wsc = (char*)d_ws;
  _Float16* hcatH = (_Float16*)wsc;
  float*    em    = (float*)(wsc + 26214400);
  float*    dn    = (float*)(wsc + 26214400 + 7987200);
  _Float16* xwH   = (_Float16*)(wsc + 34202112);
  float*    Pbuf  = (float*)(wsc + 34202112);
  const bool big  = ws_size >= (size_t)34202112 + 104857600;

  if (big) {
    hipLaunchKernelGGL(xw_kernel, dim3(200), dim3(256), 0, stream,
                       features, Wih_f, Wih_b, xwH);
    hipLaunchKernelGGL((lstm_kernel<1>), dim3(2 * B_), dim3(256), 0, stream,
                       features, Wih_f, Whh_f, bih_f, bhh_f,
                       Wih_b, Whh_b, bih_b, bhh_b, xwH, hcatH);
    hipLaunchKernelGGL(crf_chunk_kernel, dim3(B_ * NCH_), dim3(64), 0, stream,
                       hcatH, Wp, bp, lengths, trans, em, Pbuf);
    hipLaunchKernelGGL(crf_comb2_kernel, dim3(B_), dim3(256), 0, stream,
                       em, labels, lengths, start_t, end_t, trans, Pbuf, dn);
  } else {
    hipLaunchKernelGGL((lstm_kernel<0>), dim3(2 * B_), dim3(256), 0, stream,
                       features, Wih_f, Whh_f, bih_f, bhh_f,
                       Wih_b, Whh_b, bih_b, bhh_b, xwH, hcatH);
    hipLaunchKernelGGL(emis_kernel, dim3(BT_ / 256), dim3(256), 0, stream,
                       hcatH, Wp, bp, em);
    hipLaunchKernelGGL(crf_dn_kernel, dim3(B_), dim3(256), 0, stream,
                       em, labels, lengths, start_t, end_t, trans, dn);
  }
  hipLaunchKernelGGL(finalize_kernel, dim3(1), dim3(64), 0, stream,
                     dn, out);
}

// Round 16
// 638.695 us; speedup vs baseline: 1.0496x; 1.0496x over previous
//
#include <hip/hip_runtime.h>
#include <cstddef>
#include <cstdint>

#define B_ 64
#define T_ 800
#define D_ 80
#define H_ 128
#define K_ 39
#define BT_ (B_ * T_)   // 51200

// CRF chunking
#define GCH_ 32          // steps per chunk
#define NCH_ 25          // ceil((T_-1)/GCH_)
#define CHF_ 1664        // f32 stride per chunk record (40*40 data + pad; scale at [1600])

// exp2 pre-scale constants.
#define NL2E_  (-1.44269504f)
#define N2L2E_ (-2.88539008f)
#define L2E_   (1.44269504f)

typedef _Float16 h2_t  __attribute__((ext_vector_type(2)));
typedef _Float16 f16x8 __attribute__((ext_vector_type(8)));
typedef float    f32x4 __attribute__((ext_vector_type(4)));
typedef uint32_t u32x4 __attribute__((ext_vector_type(4)));

__device__ __forceinline__ float fdot2_(h2_t a, h2_t b, float c) {
#if __has_builtin(__builtin_amdgcn_fdot2)
  return __builtin_amdgcn_fdot2(a, b, c, false);
#else
  return c + (float)a.x * (float)b.x + (float)a.y * (float)b.y;
#endif
}

__device__ __forceinline__ h2_t asH2u_(uint32_t u) { return __builtin_bit_cast(h2_t, u); }

__device__ __forceinline__ float ex2_(float x) {
#if __has_builtin(__builtin_amdgcn_exp2f)
  return __builtin_amdgcn_exp2f(x);
#else
  return __builtin_exp2f(x);
#endif
}
__device__ __forceinline__ float rcpf_(float x) {
#if __has_builtin(__builtin_amdgcn_rcpf)
  return __builtin_amdgcn_rcpf(x);
#else
  return 1.0f / x;
#endif
}
__device__ __forceinline__ float tanhf_(float x) { return 2.0f / (1.0f + __expf(-2.0f * x)) - 1.0f; }

__device__ __forceinline__ float laneb_(float v, int lane) {
  return __builtin_bit_cast(float, __builtin_amdgcn_readlane(__builtin_bit_cast(int, v), lane));
}
__device__ __forceinline__ uint32_t lanebu_(uint32_t v, int lane) {
  return (uint32_t)__builtin_amdgcn_readlane((int)v, lane);
}

// VALU lane-pair swap via DPP quad_perm[1,0,3,2] (0xB1): lane 2k <-> 2k+1.
__device__ __forceinline__ float dppswap1_(float v) {
  return __builtin_bit_cast(float,
    __builtin_amdgcn_mov_dpp(__builtin_bit_cast(int, v), 0xB1, 0xF, 0xF, true));
}

// LDS-only barrier: waits LDS ops but does NOT drain vmem.
__device__ __forceinline__ void barrier_lds_() {
  asm volatile("s_waitcnt lgkmcnt(0)" ::: "memory");
  __builtin_amdgcn_s_barrier();
}

// lstm lane->gate-rows mapping: wave w, lane L: unit = w*32 + (L>>1),
// role = L&1. role0 owns (i,g) rows, role1 owns (f,o). DPP(1) pairs them.
__device__ __forceinline__ void rows_of_(int tid, int& unit, int& role, int& r0, int& r1) {
  const int w = tid >> 6, L = tid & 63;
  unit = w * 32 + (L >> 1);
  role = L & 1;
  r0 = role * H_ + unit;            // i (role0) or f (role1)
  r1 = 2 * H_ + role * H_ + unit;   // g (role0) or o (role1)
}

// ---------------------------------------------------------------------------
// xw via MFMA 16x16x32 f16, PAIRED output layout, pre-scaled, LDS-bounced
// coalesced stores (verified R14).
// ---------------------------------------------------------------------------
__global__ __launch_bounds__(256, 1)
void xw_kernel(const float* __restrict__ x,
               const float* __restrict__ Wih_f, const float* __restrict__ Wih_b,
               _Float16* __restrict__ xw)
{
  const int dir = blockIdx.x & 1;
  const int mc  = blockIdx.x >> 1;           // 0..99
  const float* W = dir ? Wih_b : Wih_f;

  const int tid  = threadIdx.x;
  const int w    = tid >> 6;
  const int lane = tid & 63;
  const int lm   = lane & 15;
  const int quad = lane >> 4;
  const int selw = w >> 1;                   // 0: i/f (.x slot), 1: g/o (.y slot)
  const int rolw = w & 1;

  f16x8 Bf[8][3];
  #pragma unroll
  for (int nt = 0; nt < 8; ++nt) {
    const int r = w * 128 + nt * 16 + lm;
    const float fac = (r >= 256 && r < 384) ? N2L2E_ : NL2E_;   // g rows: -2log2e
    #pragma unroll
    for (int kt = 0; kt < 3; ++kt) {
      const int kb = kt * 32 + quad * 8;
      #pragma unroll
      for (int j = 0; j < 8; ++j) {
        const int k = kb + j;
        Bf[nt][kt][j] = (k < D_) ? (_Float16)(fac * W[(size_t)r * D_ + k]) : (_Float16)0.0f;
      }
    }
  }

  __shared__ alignas(16) _Float16 xs[128 * 96];   // 24 KB, K padded to 96
  __shared__ alignas(16) _Float16 xo[16 * 512];   // 16 KB store-coalescing tile
  for (int i = tid; i < 128 * 96; i += 256) xs[i] = (_Float16)0.0f;

  for (int cc = 0; cc < 4; ++cc) {
    const int base = mc * 512 + cc * 128;
    __syncthreads();
    {
      const float4* src = (const float4*)(x + (size_t)base * D_);
      for (int i = tid; i < 128 * D_ / 4; i += 256) {
        float4 v = src[i];
        const int row = i / 20, col = (i % 20) * 4;
        h2_t p0, p1;
        p0.x = (_Float16)v.x; p0.y = (_Float16)v.y;
        p1.x = (_Float16)v.z; p1.y = (_Float16)v.w;
        uint2 pk;
        pk.x = __builtin_bit_cast(uint32_t, p0);
        pk.y = __builtin_bit_cast(uint32_t, p1);
        *(uint2*)&xs[row * 96 + col] = pk;
      }
    }
    __syncthreads();

    #pragma unroll
    for (int mt = 0; mt < 8; ++mt) {
      f16x8 Af[3];
      #pragma unroll
      for (int kt = 0; kt < 3; ++kt)
        Af[kt] = *(const f16x8*)&xs[(mt * 16 + lm) * 96 + kt * 32 + quad * 8];

      f32x4 acc[8];
      #pragma unroll
      for (int nt = 0; nt < 8; ++nt) acc[nt] = (f32x4){0.f, 0.f, 0.f, 0.f};
      #pragma unroll
      for (int kt = 0; kt < 3; ++kt)
        #pragma unroll
        for (int nt = 0; nt < 8; ++nt)
          acc[nt] = __builtin_amdgcn_mfma_f32_16x16x32_f16(Af[kt], Bf[nt][kt], acc[nt], 0, 0, 0);

      // scatter tile into LDS (verified ptid mapping, local rows)
      #pragma unroll
      for (int nt = 0; nt < 8; ++nt) {
        const int unit = nt * 16 + lm;
        const int pcol = ((unit >> 5) * 64 + (unit & 31) * 2 + rolw) * 2 + selw;
        #pragma unroll
        for (int rg = 0; rg < 4; ++rg)
          xo[(quad * 4 + rg) * 512 + pcol] = (_Float16)acc[nt][rg];
      }
      __syncthreads();
      {
        const size_t gbase = ((size_t)dir * BT_ + base + mt * 16) * 512;
        const uint4* src4 = (const uint4*)xo;
        uint4* dst4 = (uint4*)(xw + gbase);
        #pragma unroll
        for (int i = 0; i < 4; ++i)
          dst4[tid + i * 256] = src4[tid + i * 256];
      }
      __syncthreads();   // xo reused next tile
    }
  }
}

// ---------------------------------------------------------------------------
// Recurrent LSTM: verified R4 433us kernel.
// ---------------------------------------------------------------------------
template<int USE_XW>
__global__ __launch_bounds__(256, 1)
void lstm_kernel(const float* __restrict__ x,
                 const float* __restrict__ Wih_f, const float* __restrict__ Whh_f,
                 const float* __restrict__ bih_f, const float* __restrict__ bhh_f,
                 const float* __restrict__ Wih_b, const float* __restrict__ Whh_b,
                 const float* __restrict__ bih_b, const float* __restrict__ bhh_b,
                 const _Float16* __restrict__ xw,
                 _Float16* __restrict__ hcat)
{
  const int bb  = blockIdx.x & 63;
  const int dir = blockIdx.x >> 6;
  const float* Whh = dir ? Whh_b : Whh_f;
  const float* Wih = dir ? Wih_b : Wih_f;
  const float* bih = dir ? bih_b : bih_f;
  const float* bhh = dir ? bhh_b : bhh_f;

  const int tid  = threadIdx.x;
  const int lane = tid & 63;
  int unit, role, r0, r1; rows_of_(tid, unit, role, r0, r1);
  const float s0 = NL2E_;
  const float s1 = role ? NL2E_ : N2L2E_;
  const float qk2 = role ? 0.0f : -1.0f;

  h2_t w0[64], w1[64];
  #pragma unroll
  for (int j = 0; j < 64; ++j) {
    float2 a = *(const float2*)(Whh + (size_t)r0 * H_ + 2 * j);
    float2 d = *(const float2*)(Whh + (size_t)r1 * H_ + 2 * j);
    w0[j].x = (_Float16)(s0 * a.x); w0[j].y = (_Float16)(s0 * a.y);
    w1[j].x = (_Float16)(s1 * d.x); w1[j].y = (_Float16)(s1 * d.y);
  }
  h2_t wx0[40], wx1[40];
  if (!USE_XW) {
    #pragma unroll
    for (int i = 0; i < 40; ++i) {
      float2 a = *(const float2*)(Wih + (size_t)r0 * D_ + 2 * i);
      float2 d = *(const float2*)(Wih + (size_t)r1 * D_ + 2 * i);
      wx0[i].x = (_Float16)(s0 * a.x); wx0[i].y = (_Float16)(s0 * a.y);
      wx1[i].x = (_Float16)(s1 * d.x); wx1[i].y = (_Float16)(s1 * d.y);
    }
  }
  const float bias0 = s0 * (bih[r0] + bhh[r0]);
  const float bias1 = s1 * (bih[r1] + bhh[r1]);

  __shared__ alignas(16) _Float16 hsf[2][H_];  // double-buffered h
  __shared__ uint32_t xs2[2][64];              // fallback x staging

  if (tid < H_) hsf[0][tid] = (_Float16)0.0f;
  if (!USE_XW && tid < 64) { xs2[0][tid] = 0u; xs2[1][tid] = 0u; }
  float c = 0.0f;   // role1 owns cell state of its unit

  const uint32_t* xwdu = (const uint32_t*)xw + ((size_t)dir * BT_ + (size_t)bb * T_) * 256;
  const float*    xb   = x + (size_t)bb * T_ * D_;
  _Float16*       hb   = hcat + (size_t)bb * T_ * (2 * H_) + dir * H_;

  _Float16* hbp = hb + (size_t)(dir ? (T_ - 1) : 0) * (2 * H_);
  const ptrdiff_t hstep = dir ? -(2 * H_) : (2 * H_);
  int xoff = (dir ? (T_ - 3) : 2) * 256 + tid;     // prefetch offset for ttc=2
  const int xstep = dir ? -256 : 256;

  uint32_t xwA = 0u, xwB = 0u;
  h2_t xpend; xpend.x = (_Float16)0.f; xpend.y = (_Float16)0.f;
  {
    const int tq0 = dir ? (T_ - 1) : 0;
    const int tq1 = dir ? (T_ - 2) : 1;
    if (USE_XW) {
      xwA = xwdu[(size_t)tq0 * 256 + tid];
      xwB = xwdu[(size_t)tq1 * 256 + tid];
    } else if (tid < 40) {
      float2 v0 = *(const float2*)(xb + (size_t)tq0 * D_ + 2 * tid);
      h2_t p; p.x = (_Float16)v0.x; p.y = (_Float16)v0.y;
      xs2[0][tid] = __builtin_bit_cast(uint32_t, p);
      float2 v1 = *(const float2*)(xb + (size_t)tq1 * D_ + 2 * tid);
      xpend.x = (_Float16)v1.x; xpend.y = (_Float16)v1.y;
    }
  }
  __syncthreads();

  auto step = [&](int tt, int par, uint32_t& xwreg) {
    float a0, a1, a2, a3, b0, b1, b2, b3;
    if (USE_XW) {
      const h2_t xv = asH2u_(xwreg);
      a0 = bias0 + (float)xv.x;
      b0 = bias1 + (float)xv.y;
      a1 = a2 = a3 = 0.f; b1 = b2 = b3 = 0.f;
      xwreg = xwdu[xoff];                         // prefetch; consumed 2 steps later
    } else {
      a0 = bias0; b0 = bias1;
      a1 = a2 = a3 = 0.f; b1 = b2 = b3 = 0.f;
      if (tid < 40) {
        xs2[par ^ 1][tid] = __builtin_bit_cast(uint32_t, xpend);
        const int ttc = (tt + 2 < T_) ? (tt + 2) : (T_ - 1);
        const int tq2 = dir ? (T_ - 1 - ttc) : ttc;
        float2 v = *(const float2*)(xb + (size_t)tq2 * D_ + 2 * tid);
        xpend.x = (_Float16)v.x; xpend.y = (_Float16)v.y;
      }
      uint32_t xreg = xs2[par][lane];
      #pragma unroll
      for (int j = 0; j < 40; j += 4) {
        h2_t q0 = asH2u_(lanebu_(xreg, j));
        h2_t q1 = asH2u_(lanebu_(xreg, j + 1));
        h2_t q2 = asH2u_(lanebu_(xreg, j + 2));
        h2_t q3 = asH2u_(lanebu_(xreg, j + 3));
        a0 = fdot2_(wx0[j],     q0, a0); b0 = fdot2_(wx1[j],     q0, b0);
        a1 = fdot2_(wx0[j + 1], q1, a1); b1 = fdot2_(wx1[j + 1], q1, b1);
        a2 = fdot2_(wx0[j + 2], q2, a2); b2 = fdot2_(wx1[j + 2], q2, b2);
        a3 = fdot2_(wx0[j + 3], q3, a3); b3 = fdot2_(wx1[j + 3], q3, b3);
      }
    }

    // h @ Whh^T via uniform-address LDS broadcasts, 8 chains depth 16.
    const u32x4* hq = (const u32x4*)hsf[par];
    #pragma unroll
    for (int g = 0; g < 16; ++g) {
      const u32x4 hv = hq[g];
      a0 = fdot2_(w0[4 * g + 0], asH2u_(hv[0]), a0);
      b0 = fdot2_(w1[4 * g + 0], asH2u_(hv[0]), b0);
      a1 = fdot2_(w0[4 * g + 1], asH2u_(hv[1]), a1);
      b1 = fdot2_(w1[4 * g + 1], asH2u_(hv[1]), b1);
      a2 = fdot2_(w0[4 * g + 2], asH2u_(hv[2]), a2);
      b2 = fdot2_(w1[4 * g + 2], asH2u_(hv[2]), b2);
      a3 = fdot2_(w0[4 * g + 3], asH2u_(hv[3]), a3);
      b3 = fdot2_(w1[4 * g + 3], asH2u_(hv[3]), b3);
    }
    const float ga = (a0 + a1) + (a2 + a3);   // -log2e * (i|f)
    const float gb = (b0 + b1) + (b2 + b3);   // -2log2e*g | -log2e*o

    const float ea = ex2_(ga);
    const float sg = rcpf_(1.0f + ea);
    const float gbc = fminf(fmaxf(gb, -34.6f), 34.6f);
    const float eb = ex2_(gbc);
    const float qv = fmaf(qk2, eb, 1.0f) * rcpf_(1.0f + eb);
    const float ex = dppswap1_(sg * qv);      // role1 receives p = sig(i)*tanh(g)
    c = fmaf(sg, c, ex);                      // role1: sig(f)*c + p (role0 benign)
    const float hn = qv * tanhf_(c);          // role1: sig(o)*tanh(c)
    if (role) {
      hsf[par ^ 1][unit] = (_Float16)hn;
      hbp[unit] = (_Float16)hn;               // async store, never drained
    }
    hbp += hstep;
    if (tt + 3 < T_) xoff += xstep;           // wave-uniform clamp-advance
    barrier_lds_();
  };

  for (int tb = 0; tb < T_; tb += 2) {
    step(tb,     0, xwA);
    step(tb + 1, 1, xwB);
  }
}

// ---------------------------------------------------------------------------
// Emissions via MFMA (verified; used in both paths).
// ---------------------------------------------------------------------------
__global__ __launch_bounds__(256, 1)
void emis_kernel(const _Float16* __restrict__ hcat,
                 const float* __restrict__ Wp, const float* __restrict__ bp,
                 float* __restrict__ em)
{
  const int tid  = threadIdx.x;
  const int w    = tid >> 6;
  const int lane = tid & 63;
  const int lm   = lane & 15;
  const int quad = lane >> 4;

  f16x8 Bf[3][8];
  float bias[3];
  #pragma unroll
  for (int nt = 0; nt < 3; ++nt) {
    const int n = nt * 16 + lm;
    const bool valid = n < K_;
    bias[nt] = valid ? bp[n] : 0.0f;
    #pragma unroll
    for (int kt = 0; kt < 8; ++kt) {
      const int kb = kt * 32 + quad * 8;
      #pragma unroll
      for (int j = 0; j < 8; ++j)
        Bf[nt][kt][j] = valid ? (_Float16)Wp[(size_t)n * 256 + kb + j] : (_Float16)0.0f;
    }
  }

  #pragma unroll
  for (int q = 0; q < 4; ++q) {
    const int mt  = blockIdx.x * 16 + w * 4 + q;
    const int bt0 = mt * 16;

    f16x8 Af[8];
    const _Float16* ab = hcat + ((size_t)bt0 + lm) * 256;
    #pragma unroll
    for (int kt = 0; kt < 8; ++kt)
      Af[kt] = *(const f16x8*)(ab + kt * 32 + quad * 8);

    f32x4 acc[3];
    #pragma unroll
    for (int nt = 0; nt < 3; ++nt) acc[nt] = (f32x4){0.f, 0.f, 0.f, 0.f};
    #pragma unroll
    for (int kt = 0; kt < 8; ++kt)
      #pragma unroll
      for (int nt = 0; nt < 3; ++nt)
        acc[nt] = __builtin_amdgcn_mfma_f32_16x16x32_f16(Af[kt], Bf[nt][kt], acc[nt], 0, 0, 0);

    #pragma unroll
    for (int nt = 0; nt < 3; ++nt) {
      const int n = nt * 16 + lm;
      if (n < K_) {
        #pragma unroll
        for (int rg = 0; rg < 4; ++rg) {
          const int row = bt0 + quad * 4 + rg;
          em[(size_t)row * K_ + n] = acc[nt][rg] + bias[nt];
        }
      }
    }
  }
}

// ---------------------------------------------------------------------------
// CRF chunked partial products (verified R13/R14). R16: block 0 lane 0 also
// zeroes out[0] (stream-ordered before crf_comb2's atomicAdd).
// ---------------------------------------------------------------------------
__global__ __launch_bounds__(64, 1)
void crf_chunk_kernel(const float* __restrict__ em,
                      const int* __restrict__ lengths,
                      const float* __restrict__ trans,
                      float* __restrict__ Pbuf,
                      float* __restrict__ out)
{
  const int b    = blockIdx.x / NCH_;
  const int c    = blockIdx.x % NCH_;
  const int lane = threadIdx.x;          // 0..63
  const int lm   = lane & 15;
  const int quad = lane >> 4;
  const int len  = lengths[b];
  const int t0   = 1 + c * GCH_;
  int t1 = 1 + (c + 1) * GCH_;
  if (t1 > T_)  t1 = T_;
  if (t1 > len) t1 = len;

  if (blockIdx.x == 0 && lane == 0) out[0] = 0.0f;   // for comb's atomicAdd

  // Constant ET B-fragments (verified R13 layout).
  f16x8 Bf[3][2];
  #pragma unroll
  for (int nt = 0; nt < 3; ++nt) {
    const int n = nt * 16 + lm;
    #pragma unroll
    for (int kf = 0; kf < 2; ++kf) {
      #pragma unroll
      for (int jj = 0; jj < 8; ++jj) {
        const int j = kf * 32 + quad * 8 + jj;
        Bf[nt][kf][jj] = (j < K_ && n < K_)
          ? (_Float16)__expf(trans[j * K_ + n]) : (_Float16)0.0f;
      }
    }
  }

  // P in LDS, 48x48 padded to row stride 68 f16 (136 B: rows spread banks).
  __shared__ alignas(16) _Float16 Plds[48 * 68];
  for (int i = lane; i < 48 * 68; i += 64) Plds[i] = (_Float16)0.0f;
  if (lane < K_) Plds[lane * 68 + lane] = (_Float16)1.0f;   // identity
  asm volatile("s_waitcnt lgkmcnt(0)" ::: "memory");

  float sacc = 0.0f;
  const float* emb = em + (size_t)b * T_ * K_;

  for (int t = t0; t < t1; ++t) {
    // e'[col] = exp(em[t][col] - max_col em[t]); cols held as nt*16+lm.
    float emv[3], e3[3];
    float mloc = -1e30f;
    #pragma unroll
    for (int nt = 0; nt < 3; ++nt) {
      const int col = nt * 16 + lm;
      emv[nt] = (col < K_) ? emb[(size_t)t * K_ + col] : -1e30f;
      mloc = fmaxf(mloc, emv[nt]);
    }
    #pragma unroll
    for (int off = 8; off >= 1; off >>= 1)
      mloc = fmaxf(mloc, __shfl_xor(mloc, off));     // reduce over lm group
    #pragma unroll
    for (int nt = 0; nt < 3; ++nt) {
      const int col = nt * 16 + lm;
      e3[nt] = (col < K_) ? ex2_((emv[nt] - mloc) * L2E_) : 0.0f;
    }

    // P @ ET : 9 output tiles x 2 k-fragments.
    f32x4 acc[3][3];
    #pragma unroll
    for (int mt = 0; mt < 3; ++mt)
      #pragma unroll
      for (int nt = 0; nt < 3; ++nt)
        acc[mt][nt] = (f32x4){0.f, 0.f, 0.f, 0.f};
    #pragma unroll
    for (int kf = 0; kf < 2; ++kf) {
      f16x8 Am[3];
      #pragma unroll
      for (int mt = 0; mt < 3; ++mt)
        Am[mt] = *(const f16x8*)&Plds[(mt * 16 + lm) * 68 + kf * 32 + quad * 8];
      #pragma unroll
      for (int mt = 0; mt < 3; ++mt)
        #pragma unroll
        for (int nt = 0; nt < 3; ++nt)
          acc[mt][nt] = __builtin_amdgcn_mfma_f32_16x16x32_f16(Am[mt], Bf[nt][kf], acc[mt][nt], 0, 0, 0);
    }

    // column-scale by e', per-step max renorm (keeps f16 entries in [0,1]).
    float sv[3][3][4];
    float mx = 0.0f;
    #pragma unroll
    for (int mt = 0; mt < 3; ++mt)
      #pragma unroll
      for (int nt = 0; nt < 3; ++nt)
        #pragma unroll
        for (int rg = 0; rg < 4; ++rg) {
          const float s = acc[mt][nt][rg] * e3[nt];
          sv[mt][nt][rg] = s;
          mx = fmaxf(mx, s);
        }
    #pragma unroll
    for (int off = 32; off >= 1; off >>= 1)
      mx = fmaxf(mx, __shfl_xor(mx, off));
    const float rmx = rcpf_(mx);
    sacc += mloc - __logf(rmx);     // exact compensation of the two scalings

    // write back (D layout: row = mt*16+quad*4+rg, col = nt*16+lm).
    #pragma unroll
    for (int mt = 0; mt < 3; ++mt)
      #pragma unroll
      for (int nt = 0; nt < 3; ++nt)
        #pragma unroll
        for (int rg = 0; rg < 4; ++rg) {
          const int row = mt * 16 + quad * 4 + rg;
          const int col = nt * 16 + lm;
          Plds[row * 68 + col] = (_Float16)(sv[mt][nt][rg] * rmx);
        }
    asm volatile("s_waitcnt lgkmcnt(0)" ::: "memory");
  }

  // dump P (40x40 f32) + scale
  float* rec = Pbuf + ((size_t)(b * NCH_ + c)) * CHF_;
  for (int i = lane; i < 1600; i += 64) {
    const int r = i / 40, cc2 = i % 40;
    rec[i] = (float)Plds[r * 68 + cc2];
  }
  if (lane == 0) rec[1600] = sacc;
}

// ---------------------------------------------------------------------------
// CRF combine + numerator (verified R13). R16: the per-batch loss term is
// atomicAdd'ed into out[0] (pre-zeroed by crf_chunk), deleting the finalize
// dispatch.
// ---------------------------------------------------------------------------
__global__ __launch_bounds__(256)
void crf_comb2_kernel(const float* __restrict__ em,
                      const int* __restrict__ labels, const int* __restrict__ lengths,
                      const float* __restrict__ start_t, const float* __restrict__ end_t,
                      const float* __restrict__ trans,
                      const float* __restrict__ Pbuf,
                      float* __restrict__ out)
{
  const int b    = blockIdx.x;
  const int tid  = threadIdx.x;
  const int wv   = tid >> 6;
  const int lane = tid & 63;
  const int len  = lengths[b];
  const float* emb = em + (size_t)b * T_ * K_;

  __shared__ float s_num[3];
  __shared__ float s_den;

  if (wv == 0) {
    float a0 = (lane < K_) ? (start_t[lane] + emb[lane]) : -1e30f;
    float m = a0;
    #pragma unroll
    for (int off = 32; off > 0; off >>= 1) m = fmaxf(m, __shfl_xor(m, off));
    float av = __expf(a0 - m);        // lanes >= 39 -> 0
    float off_acc = m;

    for (int c = 0; c < NCH_; ++c) {
      const float* rec = Pbuf + ((size_t)(b * NCH_ + c)) * CHF_;
      const float pv = av;
      float s0 = 0.f, s1 = 0.f, s2 = 0.f, s3 = 0.f;
      #pragma unroll
      for (int j = 0; j < 36; j += 4) {
        s0 = fmaf(laneb_(pv, j),     rec[(j)     * 40 + lane], s0);
        s1 = fmaf(laneb_(pv, j + 1), rec[(j + 1) * 40 + lane], s1);
        s2 = fmaf(laneb_(pv, j + 2), rec[(j + 2) * 40 + lane], s2);
        s3 = fmaf(laneb_(pv, j + 3), rec[(j + 3) * 40 + lane], s3);
      }
      s0 = fmaf(laneb_(pv, 36), rec[36 * 40 + lane], s0);
      s1 = fmaf(laneb_(pv, 37), rec[37 * 40 + lane], s1);
      s2 = fmaf(laneb_(pv, 38), rec[38 * 40 + lane], s2);
      float vn = (lane < K_) ? ((s0 + s1) + (s2 + s3)) : 0.0f;
      float mx = vn;
      #pragma unroll
      for (int off = 32; off > 0; off >>= 1) mx = fmaxf(mx, __shfl_xor(mx, off));
      const float rmx = rcpf_(mx);
      av = vn * rmx;
      off_acc += rec[1600] - __logf(rmx);
    }

    float w = (lane < K_) ? av * __expf(end_t[lane]) : 0.0f;
    #pragma unroll
    for (int off = 32; off > 0; off >>= 1) w += __shfl_xor(w, off);
    if (lane == 0) s_den = off_acc + __logf(w);
  } else {
    const int idx = tid - 64;           // 0..191
    float acc = 0.0f;
    for (int t = 1 + idx; t < len; t += 192) {
      const int lp = labels[b * T_ + t - 1];
      const int lc = labels[b * T_ + t];
      acc += trans[lp * K_ + lc] + emb[(size_t)t * K_ + lc];
    }
    if (tid == 64) {
      const int l0 = labels[b * T_];
      const int ll = labels[b * T_ + len - 1];
      acc += start_t[l0] + emb[l0] + end_t[ll];
    }
    #pragma unroll
    for (int off = 32; off > 0; off >>= 1) acc += __shfl_xor(acc, off);
    if (lane == 0) s_num[wv - 1] = acc;
  }
  __syncthreads();
  if (tid == 0)
    atomicAdd(out, (s_den - (s_num[0] + s_num[1] + s_num[2])) * (1.0f / 64.0f));
}

// ---------------------------------------------------------------------------
// Old sequential CRF (verified) — small-workspace fallback only.
// ---------------------------------------------------------------------------
__global__ __launch_bounds__(256)
void crf_dn_kernel(const float* __restrict__ em,
                   const int* __restrict__ labels, const int* __restrict__ lengths,
                   const float* __restrict__ start_t, const float* __restrict__ end_t,
                   const float* __restrict__ trans,
                   float* __restrict__ dn)
{
  const int b    = blockIdx.x;
  const int tid  = threadIdx.x;
  const int wv   = tid >> 6;
  const int lane = tid & 63;
  const int len  = lengths[b];
  const float* emb = em + (size_t)b * T_ * K_;

  __shared__ float s_num[3];
  __shared__ float s_den;

  if (wv == 0) {
    float et[K_];
    #pragma unroll
    for (int j = 0; j < K_; ++j)
      et[j] = (lane < K_) ? __expf(trans[j * K_ + lane]) : 0.0f;

    float a0 = (lane < K_) ? (start_t[lane] + emb[lane]) : -1e30f;
    float m = a0;
    #pragma unroll
    for (int off = 32; off > 0; off >>= 1) m = fmaxf(m, __shfl_xor(m, off));
    float v = __expf(a0 - m);
    float off_acc = m;

    auto ldc = [&](int t) -> float {
      const int tc = (t < len) ? t : (len - 1);
      return (lane < K_) ? emb[(size_t)tc * K_ + lane] : 0.0f;
    };

    float eA = ldc(1), eB = ldc(2), eC = ldc(3), eD = ldc(4);
    float eE = ldc(5), eF = ldc(6), eG = ldc(7), eH = ldc(8);

    auto stepden = [&](float& ereg, int tt) {
      const float emc = ereg;
      ereg = ldc(tt + 8);
      if (tt < len) {
        const float pv = v;
        float s0 = 0.f, s1 = 0.f, s2 = 0.f, s3 = 0.f;
        #pragma unroll
        for (int j = 0; j < 36; j += 4) {
          s0 = fmaf(laneb_(pv, j),     et[j],     s0);
          s1 = fmaf(laneb_(pv, j + 1), et[j + 1], s1);
          s2 = fmaf(laneb_(pv, j + 2), et[j + 2], s2);
          s3 = fmaf(laneb_(pv, j + 3), et[j + 3], s3);
        }
        s0 = fmaf(laneb_(pv, 36), et[36], s0);
        s1 = fmaf(laneb_(pv, 37), et[37], s1);
        s2 = fmaf(laneb_(pv, 38), et[38], s2);
        v = ((s0 + s1) + (s2 + s3)) * __expf(emc);
        if ((tt & 3) == 0) {
          const float sc = laneb_(v, 0);
          v *= 1.0f / sc;
          off_acc += __logf(sc);
        }
      }
    };

    for (int t = 1; t < len; t += 8) {
      stepden(eA, t);     stepden(eB, t + 1);
      stepden(eC, t + 2); stepden(eD, t + 3);
      stepden(eE, t + 4); stepden(eF, t + 5);
      stepden(eG, t + 6); stepden(eH, t + 7);
    }

    float w = (lane < K_) ? v * __expf(end_t[lane]) : 0.0f;
    #pragma unroll
    for (int off = 32; off > 0; off >>= 1) w += __shfl_xor(w, off);
    if (lane == 0) s_den = off_acc + __logf(w);
  } else {
    const int idx = tid - 64;
    float acc = 0.0f;
    for (int t = 1 + idx; t < len; t += 192) {
      const int lp = labels[b * T_ + t - 1];
      const int lc = labels[b * T_ + t];
      acc += trans[lp * K_ + lc] + emb[(size_t)t * K_ + lc];
    }
    if (tid == 64) {
      const int l0 = labels[b * T_];
      const int ll = labels[b * T_ + len - 1];
      acc += start_t[l0] + emb[l0] + end_t[ll];
    }
    #pragma unroll
    for (int off = 32; off > 0; off >>= 1) acc += __shfl_xor(acc, off);
    if (lane == 0) s_num[wv - 1] = acc;
  }
  __syncthreads();
  if (tid == 0) dn[b] = s_den - (s_num[0] + s_num[1] + s_num[2]);
}

// out = mean(dn) over the 64 batch elements (one wave). Fallback path only.
__global__ void finalize_kernel(const float* __restrict__ dn, float* __restrict__ out)
{
  const int tid = threadIdx.x;   // 64
  float v = dn[tid];
  #pragma unroll
  for (int off = 32; off > 0; off >>= 1) v += __shfl_down(v, off);
  if (tid == 0) out[0] = v * (1.0f / 64.0f);
}

extern "C" void kernel_launch(void* const* d_in, const int* in_sizes, int n_in,
                              void* d_out, int out_size, void* d_ws, size_t ws_size,
                              hipStream_t stream)
{
  (void)in_sizes; (void)n_in; (void)out_size;
  const float* features = (const float*)d_in[0];
  const int*   lengths  = (const int*)d_in[1];
  const int*   labels   = (const int*)d_in[2];
  const float* Wih_f = (const float*)d_in[3];
  const float* Whh_f = (const float*)d_in[4];
  const float* bih_f = (const float*)d_in[5];
  const float* bhh_f = (const float*)d_in[6];
  const float* Wih_b = (const float*)d_in[7];
  const float* Whh_b = (const float*)d_in[8];
  const float* bih_b = (const float*)d_in[9];
  const float* bhh_b = (const float*)d_in[10];
  const float* Wp      = (const float*)d_in[11];
  const float* bp      = (const float*)d_in[12];
  const float* start_t = (const float*)d_in[13];
  const float* end_t   = (const float*)d_in[14];
  const float* trans   = (const float*)d_in[15];
  float* out = (float*)d_out;

  // ws layout (bytes): hcat f16 [0, 26214400) ; em f32 [26214400, +7987200) ;
  // dn 256 B ; xw f16 [34202112, +104857600). Pbuf overlays the xw region
  // (xw is dead after lstm completes; crf_chunk runs after emis).
  char* wsc = (char*)d_ws;
  _Float16* hcatH = (_Float16*)wsc;
  float*    em    = (float*)(wsc + 26214400);
  float*    dn    = (float*)(wsc + 26214400 + 7987200);
  _Float16* xwH   = (_Float16*)(wsc + 34202112);
  float*    Pbuf  = (float*)(wsc + 34202112);
  const bool big  = ws_size >= (size_t)34202112 + 104857600;

  if (big) {
    hipLaunchKernelGGL(xw_kernel, dim3(200), dim3(256), 0, stream,
                       features, Wih_f, Wih_b, xwH);
    hipLaunchKernelGGL((lstm_kernel<1>), dim3(2 * B_), dim3(256), 0, stream,
                       features, Wih_f, Whh_f, bih_f, bhh_f,
                       Wih_b, Whh_b, bih_b, bhh_b, xwH, hcatH);
    hipLaunchKernelGGL(emis_kernel, dim3(BT_ / 256), dim3(256), 0, stream,
                       hcatH, Wp, bp, em);
    hipLaunchKernelGGL(crf_chunk_kernel, dim3(B_ * NCH_), dim3(64), 0, stream,
                       em, lengths, trans, Pbuf, out);
    hipLaunchKernelGGL(crf_comb2_kernel, dim3(B_), dim3(256), 0, stream,
                       em, labels, lengths, start_t, end_t, trans, Pbuf, out);
  } else {
    hipLaunchKernelGGL((lstm_kernel<0>), dim3(2 * B_), dim3(256), 0, stream,
                       features, Wih_f, Whh_f, bih_f, bhh_f,
                       Wih_b, Whh_b, bih_b, bhh_b, xwH, hcatH);
    hipLaunchKernelGGL(emis_kernel, dim3(BT_ / 256), dim3(256), 0, stream,
                       hcatH, Wp, bp, em);
    hipLaunchKernelGGL(crf_dn_kernel, dim3(B_), dim3(256), 0, stream,
                       em, labels, lengths, start_t, end_t, trans, dn);
    hipLaunchKernelGGL(finalize_kernel, dim3(1), dim3(64), 0, stream,
                       dn, out);
  }
}